// Round 4
// baseline (125.173 us; speedup 1.0000x reference)
//
#include <hip/hip_runtime.h>

// x: (B, T+1, T) fp32.  pad = x[:,0,:], sig = x[:,1:,:]
// s[t] = sum_i |sig[i,t]|; w = sigmoid(pad - s)
// out[:,0,:] = w*pad; out[:,1+i,:] = (1-w[i])*sig[i,:]
//
// Block (b, stripe) owns columns [c0,c0+COLS): computes their colsums -> w,
// then scales+writes output ROWS [c0,c0+COLS) (scale of row i is 1-w[i]).
//
// 512 threads/block: 8 waves * 4 blocks/CU = 32 waves/CU (max occupancy).
// Phase 1 batches 8 independent float4 loads per iter; phase 2 batches 4 rows
// (4 loads in flight, then 4 NT stores) — explicit MLP since the compiler
// allocated only 32 VGPRs and kept ~1 load in flight.

#define TDIM 2048
#define BDIM 16
#define COLS 32          // columns (== output rows) per block
#define NTHREADS 512

typedef float floatx4 __attribute__((ext_vector_type(4)));

__global__ __launch_bounds__(NTHREADS, 8) void pb_kernel(const float* __restrict__ x,
                                                         float* __restrict__ out) {
    const int blk    = blockIdx.x;                 // 0 .. B*(T/COLS)-1
    const int b      = blk / (TDIM / COLS);
    const int stripe = blk % (TDIM / COLS);
    const int c0     = stripe * COLS;
    const int t      = threadIdx.x;

    const size_t planeStride = (size_t)(TDIM + 1) * TDIM;
    const float* xb  = x   + (size_t)b * planeStride;   // batch base
    float*       ob  = out + (size_t)b * planeStride;
    const float* sig = xb + TDIM;                       // rows 1..T of x

    // ---- Phase 1: column sums for columns [c0, c0+COLS) ----
    // 8 lanes per row (each lane loads a float4 = 4 columns), 64 rows/iter,
    // 8-deep load batch -> 8 independent float4 loads in flight per thread.
    const int li = t & 7;          // lane-in-row: 0..7
    const int g  = t >> 3;         // row group:   0..63
    const float* colp = sig + (size_t)g * TDIM + (c0 + 4 * li);

    float a0 = 0.f, a1 = 0.f, a2 = 0.f, a3 = 0.f;
    #pragma unroll
    for (int rr = 0; rr < 4; ++rr) {                   // 4 batches of 8
        floatx4 v[8];
        #pragma unroll
        for (int k = 0; k < 8; ++k)
            v[k] = *reinterpret_cast<const floatx4*>(colp + (size_t)(rr * 512 + k * 64) * TDIM);
        #pragma unroll
        for (int k = 0; k < 8; ++k) {
            a0 += fabsf(v[k].x); a1 += fabsf(v[k].y);
            a2 += fabsf(v[k].z); a3 += fabsf(v[k].w);
        }
    }

    __shared__ float lds_p[64][COLS];   // [row-group][column] partials, 8 KB
    lds_p[g][4 * li + 0] = a0;
    lds_p[g][4 * li + 1] = a1;
    lds_p[g][4 * li + 2] = a2;
    lds_p[g][4 * li + 3] = a3;

    __shared__ float lds_scale[COLS];
    __syncthreads();

    if (t < COLS) {
        float s = 0.f;
        #pragma unroll
        for (int gg = 0; gg < 64; ++gg) s += lds_p[gg][t];
        const float p = xb[c0 + t];                     // pad element
        const float w = 1.0f / (1.0f + expf(s - p));    // sigmoid(p - s)
        ob[c0 + t]    = w * p;                          // out row 0
        lds_scale[t]  = 1.0f - w;
    }
    __syncthreads();

    // ---- Phase 2: output rows [c0, c0+COLS): out[1+r][*] = scale[r]*sig[r][*] ----
    // 4 rows per iteration: 4 loads issued back-to-back, then 4 NT stores.
    const float* srcb = sig + (size_t)c0 * TDIM;
    float*       dstb = ob + TDIM + (size_t)c0 * TDIM;
    #pragma unroll
    for (int r = 0; r < COLS; r += 4) {
        floatx4 v0 = *reinterpret_cast<const floatx4*>(srcb + (size_t)(r + 0) * TDIM + 4 * t);
        floatx4 v1 = *reinterpret_cast<const floatx4*>(srcb + (size_t)(r + 1) * TDIM + 4 * t);
        floatx4 v2 = *reinterpret_cast<const floatx4*>(srcb + (size_t)(r + 2) * TDIM + 4 * t);
        floatx4 v3 = *reinterpret_cast<const floatx4*>(srcb + (size_t)(r + 3) * TDIM + 4 * t);
        const float s0 = lds_scale[r + 0];
        const float s1 = lds_scale[r + 1];
        const float s2 = lds_scale[r + 2];
        const float s3 = lds_scale[r + 3];
        v0.x *= s0; v0.y *= s0; v0.z *= s0; v0.w *= s0;
        v1.x *= s1; v1.y *= s1; v1.z *= s1; v1.w *= s1;
        v2.x *= s2; v2.y *= s2; v2.z *= s2; v2.w *= s2;
        v3.x *= s3; v3.y *= s3; v3.z *= s3; v3.w *= s3;
        __builtin_nontemporal_store(v0, reinterpret_cast<floatx4*>(dstb + (size_t)(r + 0) * TDIM + 4 * t));
        __builtin_nontemporal_store(v1, reinterpret_cast<floatx4*>(dstb + (size_t)(r + 1) * TDIM + 4 * t));
        __builtin_nontemporal_store(v2, reinterpret_cast<floatx4*>(dstb + (size_t)(r + 2) * TDIM + 4 * t));
        __builtin_nontemporal_store(v3, reinterpret_cast<floatx4*>(dstb + (size_t)(r + 3) * TDIM + 4 * t));
    }
}

extern "C" void kernel_launch(void* const* d_in, const int* in_sizes, int n_in,
                              void* d_out, int out_size, void* d_ws, size_t ws_size,
                              hipStream_t stream) {
    const float* x   = (const float*)d_in[0];
    float*       out = (float*)d_out;
    const int nblocks = BDIM * (TDIM / COLS);   // 16 * 64 = 1024
    pb_kernel<<<nblocks, NTHREADS, 0, stream>>>(x, out);
}